// Round 2
// baseline (2131.187 us; speedup 1.0000x reference)
//
#include <hip/hip_runtime.h>
#include <hip/hip_bf16.h>
#include <stdint.h>

typedef unsigned int uint32;

#define FEAT 128
#define NGRAPH 64

// ---------- graph preprocessing ----------
__global__ void k_deg(const int* __restrict__ dst, int* __restrict__ counts, int E) {
    int e = blockIdx.x * blockDim.x + threadIdx.x;
    if (e < E) atomicAdd(&counts[dst[e]], 1);
}

__global__ void k_dinv(const int* __restrict__ counts, float* __restrict__ dinv, int N) {
    int i = blockIdx.x * blockDim.x + threadIdx.x;
    if (i < N) dinv[i] = rsqrtf((float)counts[i] + 1.0f);   // deg = in-deg + self loop
}

// single-block exclusive scan of counts[N] -> rowp[N+1]
__global__ void k_scan(const int* __restrict__ counts, int* __restrict__ rowp, int N) {
    __shared__ int partial[1024];
    int t = threadIdx.x;
    int chunk = (N + 1023) / 1024;
    int lo = t * chunk, hi = min(lo + chunk, N);
    int s = 0;
    for (int i = lo; i < hi; i++) s += counts[i];
    partial[t] = s;
    __syncthreads();
    for (int off = 1; off < 1024; off <<= 1) {
        int v = (t >= off) ? partial[t - off] : 0;
        __syncthreads();
        partial[t] += v;
        __syncthreads();
    }
    int base = (t == 0) ? 0 : partial[t - 1];
    for (int i = lo; i < hi; i++) { rowp[i] = base; base += counts[i]; }
    if (t == 1023) rowp[N] = partial[1023];
}

__global__ void k_cursor(const int* __restrict__ rowp, int* __restrict__ cursor, int N) {
    int i = blockIdx.x * blockDim.x + threadIdx.x;
    if (i < N) cursor[i] = rowp[i];
}

__global__ void k_fill(const int* __restrict__ src, const int* __restrict__ dst,
                       const float* __restrict__ dinv, int* __restrict__ cursor,
                       int* __restrict__ csrc, float* __restrict__ cw, int E) {
    int e = blockIdx.x * blockDim.x + threadIdx.x;
    if (e >= E) return;
    int s = src[e], d = dst[e];
    int pos = atomicAdd(&cursor[d], 1);
    csrc[pos] = s;
    cw[pos] = dinv[s] * dinv[d];
}

// ---------- GEMM: H[N][128] = X[N][128] @ W[128][128], all fp32 ----------
// block = 256 (4 waves); wave handles 4 rows; lane owns cols (2l, 2l+1).
__global__ void k_gemm(const float* __restrict__ X, const float* __restrict__ W,
                       float* __restrict__ H, int N) {
    __shared__ float Wl[FEAT * FEAT];             // 64 KB fp32
    {   // cooperative W stage: 65536 B / 256 threads = 16 x uint4 each
        const uint4* Wg = (const uint4*)W;
        uint4* Ws = (uint4*)Wl;
        for (int i = threadIdx.x; i < FEAT * FEAT * 4 / 16; i += 256) Ws[i] = Wg[i];
    }
    __syncthreads();

    int wave = threadIdx.x >> 6, lane = threadIdx.x & 63;
    int gw = blockIdx.x * 4 + wave;
    int nw = gridDim.x * 4;

    for (int r0 = gw * 4; r0 < N; r0 += nw * 4) {
        int nr = min(4, N - r0);
        float2 xp[4];
#pragma unroll
        for (int ri = 0; ri < 4; ri++) {
            int r = r0 + ((ri < nr) ? ri : 0);
            xp[ri] = *(const float2*)(X + (long)r * FEAT + 2 * lane);
        }
        float2 acc[4] = {{0,0},{0,0},{0,0},{0,0}};
#pragma unroll 4
        for (int kk = 0; kk < 64; kk++) {
            // W rows 2kk, 2kk+1 at cols (2l, 2l+1)
            float2 w0 = *(const float2*)&Wl[(2 * kk) * FEAT + 2 * lane];
            float2 w1 = *(const float2*)&Wl[(2 * kk + 1) * FEAT + 2 * lane];
#pragma unroll
            for (int ri = 0; ri < 4; ri++) {
                float xvx = __shfl(xp[ri].x, kk);
                float xvy = __shfl(xp[ri].y, kk);
                acc[ri].x += xvx * w0.x + xvy * w1.x;
                acc[ri].y += xvx * w0.y + xvy * w1.y;
            }
        }
        for (int ri = 0; ri < nr; ri++) {
            ((float2*)(H + (long)(r0 + ri) * FEAT))[lane] = acc[ri];
        }
    }
}

// ---------- aggregation: OUT[i] = sum_{e:dst=i} H[src_e]*w_e + H[i]*dinv_i^2 + b ----------
// block = 256 (4 waves); wave per node; lane owns feats (2l, 2l+1).
__global__ void k_agg(const float* __restrict__ H, const int* __restrict__ rowp,
                      const int* __restrict__ csrc, const float* __restrict__ cw,
                      const float* __restrict__ dinv, const float* __restrict__ bias,
                      float* __restrict__ OUT, int N, int relu) {
    int wave = threadIdx.x >> 6, lane = threadIdx.x & 63;
    int i = blockIdx.x * 4 + wave;
    if (i >= N) return;
    float di = dinv[i];
    float2 h = ((const float2*)(H + (long)i * FEAT))[lane];
    float sw = di * di;                      // self-loop norm
    float2 acc = { h.x * sw, h.y * sw };
    int e0 = rowp[i], e1 = rowp[i + 1];
    for (int e = e0; e < e1; e++) {
        int s = csrc[e];
        float w = cw[e];
        float2 hs = ((const float2*)(H + (long)s * FEAT))[lane];
        acc.x += hs.x * w;
        acc.y += hs.y * w;
    }
    acc.x += bias[2 * lane];
    acc.y += bias[2 * lane + 1];
    if (relu) { acc.x = fmaxf(acc.x, 0.f); acc.y = fmaxf(acc.y, 0.f); }
    ((float2*)(OUT + (long)i * FEAT))[lane] = acc;
}

// ---------- pooling (batch is sorted): run-length accumulate, flush on boundary ----------
__global__ void k_pool(const float* __restrict__ G, const int* __restrict__ batch,
                       float* __restrict__ pool, int N) {
    int t = threadIdx.x;                     // 128
    int nb = gridDim.x;
    int chunk = (N + nb - 1) / nb;
    int lo = blockIdx.x * chunk, hi = min(lo + chunk, N);
    if (lo >= hi) return;
    float acc = 0.f;
    int cg = batch[lo];
    for (int i = lo; i < hi; i++) {
        int g = batch[i];                    // uniform broadcast load
        if (g != cg) {
            atomicAdd(&pool[cg * FEAT + t], acc);
            acc = 0.f; cg = g;
        }
        acc += G[(long)i * FEAT + t];
    }
    atomicAdd(&pool[cg * FEAT + t], acc);
}

__global__ void k_cnt(const int* __restrict__ batch, int* __restrict__ cntg, int N) {
    int i = blockIdx.x * blockDim.x + threadIdx.x;
    if (i < N) atomicAdd(&cntg[batch[i]], 1);
}

// ---------- head: emb = pool/cnt ; logits = emb @ Wlin + blin ; fp32 out ----------
__global__ void k_final(const float* __restrict__ pool, const int* __restrict__ cntg,
                        const float* __restrict__ Wlin, const float* __restrict__ blin,
                        float* __restrict__ out) {
    __shared__ float es[FEAT];
    int g = blockIdx.x, t = threadIdx.x;     // 64 blocks x 128 threads
    float c = (float)max(cntg[g], 1);
    float e = pool[g * FEAT + t] / c;
    es[t] = e;
    out[NGRAPH * 10 + g * FEAT + t] = e;     // emb chunk after 640 logits
    __syncthreads();
    if (t < 10) {
        float a = blin[t];
        for (int k = 0; k < FEAT; k++)
            a += es[k] * Wlin[k * 10 + t];
        out[g * 10 + t] = a;
    }
}

// ---------------------------------------------------------------
extern "C" void kernel_launch(void* const* d_in, const int* in_sizes, int n_in,
                              void* d_out, int out_size, void* d_ws, size_t ws_size,
                              hipStream_t stream) {
    const float* x    = (const float*)d_in[0];
    const int*   ei   = (const int*)d_in[1];
    const int*   batch= (const int*)d_in[2];
    const float* W1   = (const float*)d_in[3];
    const float* b1   = (const float*)d_in[4];
    const float* W2   = (const float*)d_in[5];
    const float* b2   = (const float*)d_in[6];
    const float* W3   = (const float*)d_in[7];
    const float* b3   = (const float*)d_in[8];
    const float* Wlin = (const float*)d_in[9];
    const float* blin = (const float*)d_in[10];

    const int N = in_sizes[2];
    const int E = in_sizes[1] / 2;
    const int* src = ei;
    const int* dst = ei + E;

    // ---- workspace carve ----
    char* w = (char*)d_ws;
    auto take = [&](size_t bytes) {
        char* p = w;
        w += (bytes + 255) & ~(size_t)255;
        return p;
    };
    int*   counts = (int*)  take((size_t)N * 4);
    float* dinv   = (float*)take((size_t)N * 4);
    int*   rowp   = (int*)  take((size_t)(N + 1) * 4);
    int*   cursor = (int*)  take((size_t)N * 4);
    int*   csrc   = (int*)  take((size_t)E * 4);
    float* cwv    = (float*)take((size_t)E * 4);
    float* hbuf   = (float*)take((size_t)N * FEAT * 4);
    float* gbuf   = (float*)take((size_t)N * FEAT * 4);
    float* pool   = (float*)take((size_t)NGRAPH * FEAT * 4);
    int*   cntg   = (int*)  take((size_t)NGRAPH * 4);
    (void)ws_size; (void)n_in; (void)out_size;

    const int be = (E + 255) / 256;
    const int bn = (N + 255) / 256;

    // zero-init accumulators
    hipMemsetAsync(counts, 0, (size_t)N * 4, stream);
    hipMemsetAsync(pool,   0, (size_t)NGRAPH * FEAT * 4, stream);
    hipMemsetAsync(cntg,   0, (size_t)NGRAPH * 4, stream);

    // graph preprocessing (CSR by dst)
    k_deg   <<<be, 256, 0, stream>>>(dst, counts, E);
    k_dinv  <<<bn, 256, 0, stream>>>(counts, dinv, N);
    k_scan  <<<1, 1024, 0, stream>>>(counts, rowp, N);
    k_cursor<<<bn, 256, 0, stream>>>(rowp, cursor, N);
    k_fill  <<<be, 256, 0, stream>>>(src, dst, dinv, cursor, csrc, cwv, E);

    const int gemm_blocks = (N + 15) / 16;
    const int agg_blocks  = (N + 3) / 4;

    // layer 1
    k_gemm<<<gemm_blocks, 256, 0, stream>>>(x, W1, hbuf, N);
    k_agg<<<agg_blocks, 256, 0, stream>>>(hbuf, rowp, csrc, cwv, dinv, b1, gbuf, N, 1);

    // layer 2
    k_gemm<<<gemm_blocks, 256, 0, stream>>>(gbuf, W2, hbuf, N);
    k_agg<<<agg_blocks, 256, 0, stream>>>(hbuf, rowp, csrc, cwv, dinv, b2, gbuf, N, 1);

    // layer 3
    k_gemm<<<gemm_blocks, 256, 0, stream>>>(gbuf, W3, hbuf, N);
    k_agg<<<agg_blocks, 256, 0, stream>>>(hbuf, rowp, csrc, cwv, dinv, b3, gbuf, N, 0);

    // pooling + head
    k_pool <<<1024, 128, 0, stream>>>(gbuf, batch, pool, N);
    k_cnt  <<<bn, 256, 0, stream>>>(batch, cntg, N);
    k_final<<<NGRAPH, 128, 0, stream>>>(pool, cntg, Wlin, blin, (float*)d_out);
}

// Round 3
// 1586.504 us; speedup vs baseline: 1.3433x; 1.3433x over previous
//
#include <hip/hip_runtime.h>
#include <hip/hip_bf16.h>
#include <stdint.h>

typedef unsigned int uint32;

#define FEAT 128
#define NGRAPH 64

// ---------- graph preprocessing ----------
__global__ void k_deg(const int* __restrict__ dst, int* __restrict__ counts, int E) {
    int e = blockIdx.x * blockDim.x + threadIdx.x;
    if (e < E) atomicAdd(&counts[dst[e]], 1);
}

__global__ void k_dinv(const int* __restrict__ counts, float* __restrict__ dinv, int N) {
    int i = blockIdx.x * blockDim.x + threadIdx.x;
    if (i < N) dinv[i] = rsqrtf((float)counts[i] + 1.0f);   // deg = in-deg + self loop
}

// single-block exclusive scan of counts[N] -> rowp[N+1]
__global__ void k_scan(const int* __restrict__ counts, int* __restrict__ rowp, int N) {
    __shared__ int partial[1024];
    int t = threadIdx.x;
    int chunk = (N + 1023) / 1024;
    int lo = t * chunk, hi = min(lo + chunk, N);
    int s = 0;
    for (int i = lo; i < hi; i++) s += counts[i];
    partial[t] = s;
    __syncthreads();
    for (int off = 1; off < 1024; off <<= 1) {
        int v = (t >= off) ? partial[t - off] : 0;
        __syncthreads();
        partial[t] += v;
        __syncthreads();
    }
    int base = (t == 0) ? 0 : partial[t - 1];
    for (int i = lo; i < hi; i++) { rowp[i] = base; base += counts[i]; }
    if (t == 1023) rowp[N] = partial[1023];
}

__global__ void k_cursor(const int* __restrict__ rowp, int* __restrict__ cursor, int N) {
    int i = blockIdx.x * blockDim.x + threadIdx.x;
    if (i < N) cursor[i] = rowp[i];
}

__global__ void k_fill(const int* __restrict__ src, const int* __restrict__ dst,
                       const float* __restrict__ dinv, int* __restrict__ cursor,
                       int* __restrict__ csrc, float* __restrict__ cw, int E) {
    int e = blockIdx.x * blockDim.x + threadIdx.x;
    if (e >= E) return;
    int s = src[e], d = dst[e];
    int pos = atomicAdd(&cursor[d], 1);
    csrc[pos] = s;
    cw[pos] = dinv[s] * dinv[d];
}

// ---------- GEMM: H[N][128] = X[N][128] @ W[128][128], all fp32 ----------
// block = 256 (4 waves); wave handles 4 rows; lane owns cols (2l, 2l+1).
__global__ void k_gemm(const float* __restrict__ X, const float* __restrict__ W,
                       float* __restrict__ H, int N) {
    __shared__ float Wl[FEAT * FEAT];             // 64 KB fp32
    {   // cooperative W stage: 65536 B / 256 threads = 16 x uint4 each
        const uint4* Wg = (const uint4*)W;
        uint4* Ws = (uint4*)Wl;
        for (int i = threadIdx.x; i < FEAT * FEAT * 4 / 16; i += 256) Ws[i] = Wg[i];
    }
    __syncthreads();

    int wave = threadIdx.x >> 6, lane = threadIdx.x & 63;
    int gw = blockIdx.x * 4 + wave;
    int nw = gridDim.x * 4;

    for (int r0 = gw * 4; r0 < N; r0 += nw * 4) {
        int nr = min(4, N - r0);
        float2 xp[4];
#pragma unroll
        for (int ri = 0; ri < 4; ri++) {
            int r = r0 + ((ri < nr) ? ri : 0);
            xp[ri] = *(const float2*)(X + (long)r * FEAT + 2 * lane);
        }
        float2 acc[4] = {{0,0},{0,0},{0,0},{0,0}};
#pragma unroll 4
        for (int kk = 0; kk < 64; kk++) {
            // W rows 2kk, 2kk+1 at cols (2l, 2l+1)
            float2 w0 = *(const float2*)&Wl[(2 * kk) * FEAT + 2 * lane];
            float2 w1 = *(const float2*)&Wl[(2 * kk + 1) * FEAT + 2 * lane];
#pragma unroll
            for (int ri = 0; ri < 4; ri++) {
                float xvx = __shfl(xp[ri].x, kk);
                float xvy = __shfl(xp[ri].y, kk);
                acc[ri].x += xvx * w0.x + xvy * w1.x;
                acc[ri].y += xvx * w0.y + xvy * w1.y;
            }
        }
        for (int ri = 0; ri < nr; ri++) {
            ((float2*)(H + (long)(r0 + ri) * FEAT))[lane] = acc[ri];
        }
    }
}

// ---------- aggregation: OUT[i] = sum_{e:dst=i} H[src_e]*w_e + H[i]*dinv_i^2 + b ----------
// block = 256 (4 waves); wave per node; lane owns feats (2l, 2l+1).
__global__ void k_agg(const float* __restrict__ H, const int* __restrict__ rowp,
                      const int* __restrict__ csrc, const float* __restrict__ cw,
                      const float* __restrict__ dinv, const float* __restrict__ bias,
                      float* __restrict__ OUT, int N, int relu) {
    int wave = threadIdx.x >> 6, lane = threadIdx.x & 63;
    int i = blockIdx.x * 4 + wave;
    if (i >= N) return;
    float di = dinv[i];
    float2 h = ((const float2*)(H + (long)i * FEAT))[lane];
    float sw = di * di;                      // self-loop norm
    float2 acc = { h.x * sw, h.y * sw };
    int e0 = rowp[i], e1 = rowp[i + 1];
    for (int e = e0; e < e1; e++) {
        int s = csrc[e];
        float w = cw[e];
        float2 hs = ((const float2*)(H + (long)s * FEAT))[lane];
        acc.x += hs.x * w;
        acc.y += hs.y * w;
    }
    acc.x += bias[2 * lane];
    acc.y += bias[2 * lane + 1];
    if (relu) { acc.x = fmaxf(acc.x, 0.f); acc.y = fmaxf(acc.y, 0.f); }
    ((float2*)(OUT + (long)i * FEAT))[lane] = acc;
}

// ---------- pooling (batch sorted): run-length accumulate, flush on boundary ----------
// Also counts nodes per graph (thread 0) — replaces the 524 us k_cnt histogram
// whose sorted-batch same-address atomics serialized 64-wide per wave.
__global__ void k_pool(const float* __restrict__ G, const int* __restrict__ batch,
                       float* __restrict__ pool, int* __restrict__ cntg, int N) {
    int t = threadIdx.x;                     // 128
    int nb = gridDim.x;
    int chunk = (N + nb - 1) / nb;
    int lo = blockIdx.x * chunk, hi = min(lo + chunk, N);
    if (lo >= hi) return;
    float acc = 0.f;
    int cnt = 0;
    int cg = batch[lo];
    for (int i = lo; i < hi; i++) {
        int g = batch[i];                    // uniform broadcast load
        if (g != cg) {
            atomicAdd(&pool[cg * FEAT + t], acc);
            if (t == 0) atomicAdd(&cntg[cg], cnt);
            acc = 0.f; cnt = 0; cg = g;
        }
        acc += G[(long)i * FEAT + t];
        cnt++;
    }
    atomicAdd(&pool[cg * FEAT + t], acc);
    if (t == 0) atomicAdd(&cntg[cg], cnt);
}

// ---------- head: emb = pool/cnt ; logits = emb @ Wlin + blin ; fp32 out ----------
__global__ void k_final(const float* __restrict__ pool, const int* __restrict__ cntg,
                        const float* __restrict__ Wlin, const float* __restrict__ blin,
                        float* __restrict__ out) {
    __shared__ float es[FEAT];
    int g = blockIdx.x, t = threadIdx.x;     // 64 blocks x 128 threads
    float c = (float)max(cntg[g], 1);
    float e = pool[g * FEAT + t] / c;
    es[t] = e;
    out[NGRAPH * 10 + g * FEAT + t] = e;     // emb chunk after 640 logits
    __syncthreads();
    if (t < 10) {
        float a = blin[t];
        for (int k = 0; k < FEAT; k++)
            a += es[k] * Wlin[k * 10 + t];
        out[g * 10 + t] = a;
    }
}

// ---------------------------------------------------------------
extern "C" void kernel_launch(void* const* d_in, const int* in_sizes, int n_in,
                              void* d_out, int out_size, void* d_ws, size_t ws_size,
                              hipStream_t stream) {
    const float* x    = (const float*)d_in[0];
    const int*   ei   = (const int*)d_in[1];
    const int*   batch= (const int*)d_in[2];
    const float* W1   = (const float*)d_in[3];
    const float* b1   = (const float*)d_in[4];
    const float* W2   = (const float*)d_in[5];
    const float* b2   = (const float*)d_in[6];
    const float* W3   = (const float*)d_in[7];
    const float* b3   = (const float*)d_in[8];
    const float* Wlin = (const float*)d_in[9];
    const float* blin = (const float*)d_in[10];

    const int N = in_sizes[2];
    const int E = in_sizes[1] / 2;
    const int* src = ei;
    const int* dst = ei + E;

    // ---- workspace carve ----
    char* w = (char*)d_ws;
    auto take = [&](size_t bytes) {
        char* p = w;
        w += (bytes + 255) & ~(size_t)255;
        return p;
    };
    int*   counts = (int*)  take((size_t)N * 4);
    float* dinv   = (float*)take((size_t)N * 4);
    int*   rowp   = (int*)  take((size_t)(N + 1) * 4);
    int*   cursor = (int*)  take((size_t)N * 4);
    int*   csrc   = (int*)  take((size_t)E * 4);
    float* cwv    = (float*)take((size_t)E * 4);
    float* hbuf   = (float*)take((size_t)N * FEAT * 4);
    float* gbuf   = (float*)take((size_t)N * FEAT * 4);
    float* pool   = (float*)take((size_t)NGRAPH * FEAT * 4);
    int*   cntg   = (int*)  take((size_t)NGRAPH * 4);
    (void)ws_size; (void)n_in; (void)out_size;

    const int be = (E + 255) / 256;
    const int bn = (N + 255) / 256;

    // zero-init accumulators
    hipMemsetAsync(counts, 0, (size_t)N * 4, stream);
    hipMemsetAsync(pool,   0, (size_t)NGRAPH * FEAT * 4, stream);
    hipMemsetAsync(cntg,   0, (size_t)NGRAPH * 4, stream);

    // graph preprocessing (CSR by dst)
    k_deg   <<<be, 256, 0, stream>>>(dst, counts, E);
    k_dinv  <<<bn, 256, 0, stream>>>(counts, dinv, N);
    k_scan  <<<1, 1024, 0, stream>>>(counts, rowp, N);
    k_cursor<<<bn, 256, 0, stream>>>(rowp, cursor, N);
    k_fill  <<<be, 256, 0, stream>>>(src, dst, dinv, cursor, csrc, cwv, E);

    const int gemm_blocks = (N + 15) / 16;
    const int agg_blocks  = (N + 3) / 4;

    // layer 1
    k_gemm<<<gemm_blocks, 256, 0, stream>>>(x, W1, hbuf, N);
    k_agg<<<agg_blocks, 256, 0, stream>>>(hbuf, rowp, csrc, cwv, dinv, b1, gbuf, N, 1);

    // layer 2
    k_gemm<<<gemm_blocks, 256, 0, stream>>>(gbuf, W2, hbuf, N);
    k_agg<<<agg_blocks, 256, 0, stream>>>(hbuf, rowp, csrc, cwv, dinv, b2, gbuf, N, 1);

    // layer 3
    k_gemm<<<gemm_blocks, 256, 0, stream>>>(gbuf, W3, hbuf, N);
    k_agg<<<agg_blocks, 256, 0, stream>>>(hbuf, rowp, csrc, cwv, dinv, b3, gbuf, N, 0);

    // pooling + head
    k_pool <<<1024, 128, 0, stream>>>(gbuf, batch, pool, cntg, N);
    k_final<<<NGRAPH, 128, 0, stream>>>(pool, cntg, Wlin, blin, (float*)d_out);
}

// Round 4
// 1014.906 us; speedup vs baseline: 2.0999x; 1.5632x over previous
//
#include <hip/hip_runtime.h>
#include <hip/hip_bf16.h>
#include <stdint.h>

typedef unsigned int uint32;
typedef __attribute__((ext_vector_type(8))) short short8;   // 8 bf16 = 4 VGPRs
typedef __attribute__((ext_vector_type(4))) float float4v;  // MFMA C/D

#define FEAT 128
#define NGRAPH 64

// ---------- bf16 helpers ----------
__device__ __forceinline__ float bf2f_lo(uint32 v) {        // low 16 bits -> float
    union { uint32 i; float f; } u; u.i = v << 16; return u.f;
}
__device__ __forceinline__ float bf2f_hi(uint32 v) {        // high 16 bits -> float
    union { uint32 i; float f; } u; u.i = v & 0xffff0000u; return u.f;
}
__device__ __forceinline__ unsigned short f2bf(float f) {
    uint32 u = __builtin_bit_cast(uint32, f);
    uint32 r = (u + 0x7fffu + ((u >> 16) & 1u)) >> 16;      // RNE
    return (unsigned short)r;
}
__device__ __forceinline__ uint32 f2bf2(float lo, float hi) {
    return (uint32)f2bf(lo) | ((uint32)f2bf(hi) << 16);
}

// ---------- graph preprocessing ----------
__global__ void k_deg(const int* __restrict__ dst, int* __restrict__ counts, int E) {
    int e = blockIdx.x * blockDim.x + threadIdx.x;
    if (e < E) atomicAdd(&counts[dst[e]], 1);
}

__global__ void k_dinv(const int* __restrict__ counts, float* __restrict__ dinv, int N) {
    int i = blockIdx.x * blockDim.x + threadIdx.x;
    if (i < N) dinv[i] = rsqrtf((float)counts[i] + 1.0f);   // deg = in-deg + self loop
}

// single-block exclusive scan of counts[N] -> rowp[N+1]
__global__ void k_scan(const int* __restrict__ counts, int* __restrict__ rowp, int N) {
    __shared__ int partial[1024];
    int t = threadIdx.x;
    int chunk = (N + 1023) / 1024;
    int lo = t * chunk, hi = min(lo + chunk, N);
    int s = 0;
    for (int i = lo; i < hi; i++) s += counts[i];
    partial[t] = s;
    __syncthreads();
    for (int off = 1; off < 1024; off <<= 1) {
        int v = (t >= off) ? partial[t - off] : 0;
        __syncthreads();
        partial[t] += v;
        __syncthreads();
    }
    int base = (t == 0) ? 0 : partial[t - 1];
    for (int i = lo; i < hi; i++) { rowp[i] = base; base += counts[i]; }
    if (t == 1023) rowp[N] = partial[1023];
}

__global__ void k_cursor(const int* __restrict__ rowp, int* __restrict__ cursor, int N) {
    int i = blockIdx.x * blockDim.x + threadIdx.x;
    if (i < N) cursor[i] = rowp[i];
}

__global__ void k_fill(const int* __restrict__ src, const int* __restrict__ dst,
                       const float* __restrict__ dinv, int* __restrict__ cursor,
                       int* __restrict__ csrc, float* __restrict__ cw, int E) {
    int e = blockIdx.x * blockDim.x + threadIdx.x;
    if (e >= E) return;
    int s = src[e], d = dst[e];
    int pos = atomicAdd(&cursor[d], 1);
    csrc[pos] = s;
    cw[pos] = dinv[s] * dinv[d];
}

// ---------- cast x f32 -> bf16 (packed) ----------
__global__ void k_cast(const float* __restrict__ X, uint32* __restrict__ Xb, long n2) {
    long i = (long)blockIdx.x * blockDim.x + threadIdx.x;   // index of bf16-pair
    long stride = (long)gridDim.x * blockDim.x;
    for (; i < n2; i += stride) {
        float2 v = *(const float2*)(X + 2 * i);
        Xb[i] = f2bf2(v.x, v.y);
    }
}

// ---------- pre-swizzle W (f32 [k][n], 128x128) into MFMA B-fragment order, bf16 ----
// out entry e = (kt*8 + ct)*64 + lane  holds 8 bf16: W[kt*32 + (lane>>4)*8 + j][ct*16 + (lane&15)]
__global__ void k_wswz(const float* __restrict__ W, unsigned short* __restrict__ out) {
    int e = blockIdx.x * blockDim.x + threadIdx.x;          // 2048 entries
    if (e >= 2048) return;
    int kt = e >> 9, ct = (e >> 6) & 7, lane = e & 63;
    int krow = kt * 32 + (lane >> 4) * 8;
    int col = ct * 16 + (lane & 15);
#pragma unroll
    for (int j = 0; j < 8; j++)
        out[e * 8 + j] = f2bf(W[(krow + j) * FEAT + col]);
}

// ---------- MFMA GEMM: H[N][128] = X[N][128] @ W[128][128]; bf16 in, bf16 out ----------
// block = 256 (4 waves); wave computes 16 rows x 128 cols; grid = ceil(N/64).
__global__ void k_gemm(const uint32* __restrict__ Xb,           // packed bf16 pairs
                       const unsigned short* __restrict__ Wswz, // pre-swizzled bf16
                       unsigned short* __restrict__ Hb, int N) {
    __shared__ unsigned short Wl[FEAT * FEAT];                  // 32 KB
    {   // cooperative stage: 2048 x 16B
        const uint4* Wg = (const uint4*)Wswz;
        uint4* Ws = (uint4*)Wl;
        for (int i = threadIdx.x; i < 2048; i += 256) Ws[i] = Wg[i];
    }
    __syncthreads();

    int wave = threadIdx.x >> 6, lane = threadIdx.x & 63;
    int r0 = (blockIdx.x * 4 + wave) * 16;
    if (r0 >= N) return;
    int m = lane & 15, q = lane >> 4;

    // A fragments: a[kt] = X[r0+m][kt*32 + q*8 .. +8)
    int arow = r0 + m; if (arow >= N) arow = N - 1;
    const short8* Arow = (const short8*)((const unsigned short*)Xb + (long)arow * FEAT);
    short8 a0 = Arow[q + 0];        // kt=0: elems q*8 within first 32 => index q
    short8 a1 = Arow[4 + q];        // kt=1
    short8 a2 = Arow[8 + q];        // kt=2
    short8 a3 = Arow[12 + q];       // kt=3

    const short8* Bl = (const short8*)Wl;
    float4v acc[8];
#pragma unroll
    for (int ct = 0; ct < 8; ct++) acc[ct] = (float4v){0.f, 0.f, 0.f, 0.f};

#pragma unroll
    for (int ct = 0; ct < 8; ct++) {
        acc[ct] = __builtin_amdgcn_mfma_f32_16x16x32_bf16(a0, Bl[(0 * 8 + ct) * 64 + lane], acc[ct], 0, 0, 0);
        acc[ct] = __builtin_amdgcn_mfma_f32_16x16x32_bf16(a1, Bl[(1 * 8 + ct) * 64 + lane], acc[ct], 0, 0, 0);
        acc[ct] = __builtin_amdgcn_mfma_f32_16x16x32_bf16(a2, Bl[(2 * 8 + ct) * 64 + lane], acc[ct], 0, 0, 0);
        acc[ct] = __builtin_amdgcn_mfma_f32_16x16x32_bf16(a3, Bl[(3 * 8 + ct) * 64 + lane], acc[ct], 0, 0, 0);
    }

    // C/D layout: col = lane&15, row = q*4 + reg
#pragma unroll
    for (int ct = 0; ct < 8; ct++) {
#pragma unroll
        for (int reg = 0; reg < 4; reg++) {
            int row = r0 + q * 4 + reg;
            if (row < N) Hb[(long)row * FEAT + ct * 16 + m] = f2bf(acc[ct][reg]);
        }
    }
}

// ---------- aggregation: OUT[i] = sum_{e:dst=i} H[src_e]*w_e + H[i]*dinv_i^2 + b ----------
// bf16 H in, bf16 OUT; fp32 accumulate. block = 256 (4 waves); wave per node.
__global__ void k_agg(const uint32* __restrict__ Hb,   // packed bf16 pairs [N][64]
                      const int* __restrict__ rowp,
                      const int* __restrict__ csrc, const float* __restrict__ cw,
                      const float* __restrict__ dinv, const float* __restrict__ bias,
                      uint32* __restrict__ OUTb, int N, int relu) {
    int wave = threadIdx.x >> 6, lane = threadIdx.x & 63;
    int i = blockIdx.x * 4 + wave;
    if (i >= N) return;
    float di = dinv[i];
    uint32 hv = Hb[(long)i * 64 + lane];
    float sw = di * di;                      // self-loop norm
    float ax = bf2f_lo(hv) * sw, ay = bf2f_hi(hv) * sw;
    int e0 = rowp[i], e1 = rowp[i + 1];
    for (int e = e0; e < e1; e++) {
        int s = csrc[e];
        float w = cw[e];
        uint32 hs = Hb[(long)s * 64 + lane];
        ax += bf2f_lo(hs) * w;
        ay += bf2f_hi(hs) * w;
    }
    ax += bias[2 * lane];
    ay += bias[2 * lane + 1];
    if (relu) { ax = fmaxf(ax, 0.f); ay = fmaxf(ay, 0.f); }
    OUTb[(long)i * 64 + lane] = f2bf2(ax, ay);
}

// ---------- pooling (batch sorted): run-length accumulate + count, flush on boundary ---
__global__ void k_pool(const uint32* __restrict__ Gb, const int* __restrict__ batch,
                       float* __restrict__ pool, int* __restrict__ cntg, int N) {
    int t = threadIdx.x;                     // 64 threads: feat pair t
    int nb = gridDim.x;
    int chunk = (N + nb - 1) / nb;
    int lo = blockIdx.x * chunk, hi = min(lo + chunk, N);
    if (lo >= hi) return;
    float ax = 0.f, ay = 0.f;
    int cnt = 0;
    int cg = batch[lo];
    for (int i = lo; i < hi; i++) {
        int g = batch[i];
        if (g != cg) {
            atomicAdd(&pool[cg * FEAT + 2 * t], ax);
            atomicAdd(&pool[cg * FEAT + 2 * t + 1], ay);
            if (t == 0) atomicAdd(&cntg[cg], cnt);
            ax = ay = 0.f; cnt = 0; cg = g;
        }
        uint32 v = Gb[(long)i * 64 + t];
        ax += bf2f_lo(v); ay += bf2f_hi(v);
        cnt++;
    }
    atomicAdd(&pool[cg * FEAT + 2 * t], ax);
    atomicAdd(&pool[cg * FEAT + 2 * t + 1], ay);
    if (t == 0) atomicAdd(&cntg[cg], cnt);
}

// ---------- head: emb = pool/cnt ; logits = emb @ Wlin + blin ; fp32 out ----------
__global__ void k_final(const float* __restrict__ pool, const int* __restrict__ cntg,
                        const float* __restrict__ Wlin, const float* __restrict__ blin,
                        float* __restrict__ out) {
    __shared__ float es[FEAT];
    int g = blockIdx.x, t = threadIdx.x;     // 64 blocks x 128 threads
    float c = (float)max(cntg[g], 1);
    float e = pool[g * FEAT + t] / c;
    es[t] = e;
    out[NGRAPH * 10 + g * FEAT + t] = e;     // emb chunk after 640 logits
    __syncthreads();
    if (t < 10) {
        float a = blin[t];
        for (int k = 0; k < FEAT; k++)
            a += es[k] * Wlin[k * 10 + t];
        out[g * 10 + t] = a;
    }
}

// ---------------------------------------------------------------
extern "C" void kernel_launch(void* const* d_in, const int* in_sizes, int n_in,
                              void* d_out, int out_size, void* d_ws, size_t ws_size,
                              hipStream_t stream) {
    const float* x    = (const float*)d_in[0];
    const int*   ei   = (const int*)d_in[1];
    const int*   batch= (const int*)d_in[2];
    const float* W1   = (const float*)d_in[3];
    const float* b1   = (const float*)d_in[4];
    const float* W2   = (const float*)d_in[5];
    const float* b2   = (const float*)d_in[6];
    const float* W3   = (const float*)d_in[7];
    const float* b3   = (const float*)d_in[8];
    const float* Wlin = (const float*)d_in[9];
    const float* blin = (const float*)d_in[10];

    const int N = in_sizes[2];
    const int E = in_sizes[1] / 2;
    const int* src = ei;
    const int* dst = ei + E;

    // ---- workspace carve ----
    char* w = (char*)d_ws;
    auto take = [&](size_t bytes) {
        char* p = w;
        w += (bytes + 255) & ~(size_t)255;
        return p;
    };
    int*    counts = (int*)   take((size_t)N * 4);
    float*  dinv   = (float*) take((size_t)N * 4);
    int*    rowp   = (int*)   take((size_t)(N + 1) * 4);
    int*    cursor = (int*)   take((size_t)N * 4);
    int*    csrc   = (int*)   take((size_t)E * 4);
    float*  cwv    = (float*) take((size_t)E * 4);
    uint32* xb     = (uint32*)take((size_t)N * FEAT * 2);
    uint32* hbuf   = (uint32*)take((size_t)N * FEAT * 2);
    uint32* gbuf   = (uint32*)take((size_t)N * FEAT * 2);
    unsigned short* w1s = (unsigned short*)take(FEAT * FEAT * 2);
    unsigned short* w2s = (unsigned short*)take(FEAT * FEAT * 2);
    unsigned short* w3s = (unsigned short*)take(FEAT * FEAT * 2);
    float*  pool   = (float*) take((size_t)NGRAPH * FEAT * 4);
    int*    cntg   = (int*)   take((size_t)NGRAPH * 4);
    (void)ws_size; (void)n_in; (void)out_size;

    const int be = (E + 255) / 256;
    const int bn = (N + 255) / 256;

    hipMemsetAsync(counts, 0, (size_t)N * 4, stream);
    hipMemsetAsync(pool,   0, (size_t)NGRAPH * FEAT * 4, stream);
    hipMemsetAsync(cntg,   0, (size_t)NGRAPH * 4, stream);

    // graph preprocessing (CSR by dst)
    k_deg   <<<be, 256, 0, stream>>>(dst, counts, E);
    k_dinv  <<<bn, 256, 0, stream>>>(counts, dinv, N);
    k_scan  <<<1, 1024, 0, stream>>>(counts, rowp, N);
    k_cursor<<<bn, 256, 0, stream>>>(rowp, cursor, N);
    k_fill  <<<be, 256, 0, stream>>>(src, dst, dinv, cursor, csrc, cwv, E);

    // casts / weight swizzles
    k_cast<<<2048, 256, 0, stream>>>(x, xb, (long)N * FEAT / 2);
    k_wswz<<<8, 256, 0, stream>>>(W1, w1s);
    k_wswz<<<8, 256, 0, stream>>>(W2, w2s);
    k_wswz<<<8, 256, 0, stream>>>(W3, w3s);

    const int gemm_blocks = (N + 63) / 64;
    const int agg_blocks  = (N + 3) / 4;

    // layer 1
    k_gemm<<<gemm_blocks, 256, 0, stream>>>(xb, w1s, (unsigned short*)hbuf, N);
    k_agg <<<agg_blocks, 256, 0, stream>>>(hbuf, rowp, csrc, cwv, dinv, b1, gbuf, N, 1);
    // layer 2
    k_gemm<<<gemm_blocks, 256, 0, stream>>>(gbuf, w2s, (unsigned short*)hbuf, N);
    k_agg <<<agg_blocks, 256, 0, stream>>>(hbuf, rowp, csrc, cwv, dinv, b2, gbuf, N, 1);
    // layer 3
    k_gemm<<<gemm_blocks, 256, 0, stream>>>(gbuf, w3s, (unsigned short*)hbuf, N);
    k_agg <<<agg_blocks, 256, 0, stream>>>(hbuf, rowp, csrc, cwv, dinv, b3, gbuf, N, 0);

    // pooling + head
    k_pool <<<1024, 64, 0, stream>>>(gbuf, batch, pool, cntg, N);
    k_final<<<NGRAPH, 128, 0, stream>>>(pool, cntg, Wlin, blin, (float*)d_out);
}

// Round 5
// 837.769 us; speedup vs baseline: 2.5439x; 1.2114x over previous
//
#include <hip/hip_runtime.h>
#include <hip/hip_bf16.h>
#include <stdint.h>

typedef unsigned int uint32;
typedef __attribute__((ext_vector_type(8))) short short8;   // 8 bf16 = 4 VGPRs
typedef __attribute__((ext_vector_type(4))) float float4v;  // MFMA C/D

#define FEAT 128
#define NGRAPH 64
#define SBLK 256     // scan blocks
#define STHR 256     // scan threads/block
#define SSEG 2       // elements per thread (256*256*2 = 131072 >= N)

// ---------- bf16 helpers ----------
__device__ __forceinline__ float bf2f_lo(uint32 v) {
    union { uint32 i; float f; } u; u.i = v << 16; return u.f;
}
__device__ __forceinline__ float bf2f_hi(uint32 v) {
    union { uint32 i; float f; } u; u.i = v & 0xffff0000u; return u.f;
}
__device__ __forceinline__ unsigned short f2bf(float f) {
    uint32 u = __builtin_bit_cast(uint32, f);
    uint32 r = (u + 0x7fffu + ((u >> 16) & 1u)) >> 16;      // RNE
    return (unsigned short)r;
}
__device__ __forceinline__ uint32 f2bf2(float lo, float hi) {
    return (uint32)f2bf(lo) | ((uint32)f2bf(hi) << 16);
}

// ---------- graph preprocessing ----------
__global__ void k_deg(const int* __restrict__ dst, int* __restrict__ counts, int E) {
    int e = blockIdx.x * blockDim.x + threadIdx.x;
    if (e < E) atomicAdd(&counts[dst[e]], 1);
}

__global__ void k_dinv(const int* __restrict__ counts, float* __restrict__ dinv, int N) {
    int i = blockIdx.x * blockDim.x + threadIdx.x;
    if (i < N) dinv[i] = rsqrtf((float)counts[i] + 1.0f);   // deg = in-deg + self loop
}

// ---- multi-block exclusive scan (replaces 161 us single-block k_scan @0.16% occupancy) ----
// phase a: per-thread sums + block-level scan -> tbase (exclusive within block), bsum
__global__ void k_scan_a(const int* __restrict__ counts, int* __restrict__ tbase,
                         int* __restrict__ bsum, int N) {
    __shared__ int sc[STHR];
    int t = threadIdx.x, b = blockIdx.x;
    int g = b * STHR + t;
    int lo = g * SSEG;
    int s = 0;
#pragma unroll
    for (int j = 0; j < SSEG; j++) {
        int i = lo + j;
        if (i < N) s += counts[i];
    }
    sc[t] = s;
    __syncthreads();
    for (int off = 1; off < STHR; off <<= 1) {
        int v = (t >= off) ? sc[t - off] : 0;
        __syncthreads();
        sc[t] += v;
        __syncthreads();
    }
    tbase[g] = sc[t] - s;                    // exclusive base within block
    if (t == STHR - 1) bsum[b] = sc[t];
}

// phase b: scan the 256 block sums; also writes rowp[N] = total
__global__ void k_scan_b(const int* __restrict__ bsum, int* __restrict__ bbase,
                         int* __restrict__ rowp, int N) {
    __shared__ int sc[SBLK];
    int t = threadIdx.x;
    int s = bsum[t];
    sc[t] = s;
    __syncthreads();
    for (int off = 1; off < SBLK; off <<= 1) {
        int v = (t >= off) ? sc[t - off] : 0;
        __syncthreads();
        sc[t] += v;
        __syncthreads();
    }
    bbase[t] = sc[t] - s;
    if (t == SBLK - 1) rowp[N] = sc[t];
}

// phase c: write rowp[i] (and cursor[i] — folds old k_cursor pass)
__global__ void k_scan_c(const int* __restrict__ counts, const int* __restrict__ tbase,
                         const int* __restrict__ bbase, int* __restrict__ rowp,
                         int* __restrict__ cursor, int N) {
    int t = threadIdx.x, b = blockIdx.x;
    int g = b * STHR + t;
    int base = bbase[b] + tbase[g];
    int lo = g * SSEG;
#pragma unroll
    for (int j = 0; j < SSEG; j++) {
        int i = lo + j;
        if (i < N) { rowp[i] = base; cursor[i] = base; base += counts[i]; }
    }
}

__global__ void k_fill(const int* __restrict__ src, const int* __restrict__ dst,
                       const float* __restrict__ dinv, int* __restrict__ cursor,
                       int* __restrict__ csrc, float* __restrict__ cw, int E) {
    int e = blockIdx.x * blockDim.x + threadIdx.x;
    if (e >= E) return;
    int s = src[e], d = dst[e];
    int pos = atomicAdd(&cursor[d], 1);
    csrc[pos] = s;
    cw[pos] = dinv[s] * dinv[d];
}

// ---------- cast x f32 -> bf16 (packed) ----------
__global__ void k_cast(const float* __restrict__ X, uint32* __restrict__ Xb, long n2) {
    long i = (long)blockIdx.x * blockDim.x + threadIdx.x;
    long stride = (long)gridDim.x * blockDim.x;
    for (; i < n2; i += stride) {
        float2 v = *(const float2*)(X + 2 * i);
        Xb[i] = f2bf2(v.x, v.y);
    }
}

// ---------- pre-swizzle W (f32 [k][n], 128x128) into MFMA B-fragment order, bf16 ----
__global__ void k_wswz(const float* __restrict__ W, unsigned short* __restrict__ out) {
    int e = blockIdx.x * blockDim.x + threadIdx.x;          // 2048 entries
    if (e >= 2048) return;
    int kt = e >> 9, ct = (e >> 6) & 7, lane = e & 63;
    int krow = kt * 32 + (lane >> 4) * 8;
    int col = ct * 16 + (lane & 15);
#pragma unroll
    for (int j = 0; j < 8; j++)
        out[e * 8 + j] = f2bf(W[(krow + j) * FEAT + col]);
}

// ---------- MFMA GEMM: H[N][128] = X[N][128] @ W[128][128]; bf16 in, bf16 out ----------
__global__ void k_gemm(const uint32* __restrict__ Xb,
                       const unsigned short* __restrict__ Wswz,
                       unsigned short* __restrict__ Hb, int N) {
    __shared__ unsigned short Wl[FEAT * FEAT];              // 32 KB
    {
        const uint4* Wg = (const uint4*)Wswz;
        uint4* Ws = (uint4*)Wl;
        for (int i = threadIdx.x; i < 2048; i += 256) Ws[i] = Wg[i];
    }
    __syncthreads();

    int wave = threadIdx.x >> 6, lane = threadIdx.x & 63;
    int r0 = (blockIdx.x * 4 + wave) * 16;
    if (r0 >= N) return;
    int m = lane & 15, q = lane >> 4;

    int arow = r0 + m; if (arow >= N) arow = N - 1;
    const short8* Arow = (const short8*)((const unsigned short*)Xb + (long)arow * FEAT);
    short8 a0 = Arow[q + 0];
    short8 a1 = Arow[4 + q];
    short8 a2 = Arow[8 + q];
    short8 a3 = Arow[12 + q];

    const short8* Bl = (const short8*)Wl;
    float4v acc[8];
#pragma unroll
    for (int ct = 0; ct < 8; ct++) acc[ct] = (float4v){0.f, 0.f, 0.f, 0.f};

#pragma unroll
    for (int ct = 0; ct < 8; ct++) {
        acc[ct] = __builtin_amdgcn_mfma_f32_16x16x32_bf16(a0, Bl[(0 * 8 + ct) * 64 + lane], acc[ct], 0, 0, 0);
        acc[ct] = __builtin_amdgcn_mfma_f32_16x16x32_bf16(a1, Bl[(1 * 8 + ct) * 64 + lane], acc[ct], 0, 0, 0);
        acc[ct] = __builtin_amdgcn_mfma_f32_16x16x32_bf16(a2, Bl[(2 * 8 + ct) * 64 + lane], acc[ct], 0, 0, 0);
        acc[ct] = __builtin_amdgcn_mfma_f32_16x16x32_bf16(a3, Bl[(3 * 8 + ct) * 64 + lane], acc[ct], 0, 0, 0);
    }

    // C/D layout: col = lane&15, row = q*4 + reg
#pragma unroll
    for (int ct = 0; ct < 8; ct++) {
#pragma unroll
        for (int reg = 0; reg < 4; reg++) {
            int row = r0 + q * 4 + reg;
            if (row < N) Hb[(long)row * FEAT + ct * 16 + m] = f2bf(acc[ct][reg]);
        }
    }
}

// ---------- aggregation ----------
__global__ void k_agg(const uint32* __restrict__ Hb,
                      const int* __restrict__ rowp,
                      const int* __restrict__ csrc, const float* __restrict__ cw,
                      const float* __restrict__ dinv, const float* __restrict__ bias,
                      uint32* __restrict__ OUTb, int N, int relu) {
    int wave = threadIdx.x >> 6, lane = threadIdx.x & 63;
    int i = blockIdx.x * 4 + wave;
    if (i >= N) return;
    float di = dinv[i];
    uint32 hv = Hb[(long)i * 64 + lane];
    float sw = di * di;
    float ax = bf2f_lo(hv) * sw, ay = bf2f_hi(hv) * sw;
    int e0 = rowp[i], e1 = rowp[i + 1];
    for (int e = e0; e < e1; e++) {
        int s = csrc[e];
        float w = cw[e];
        uint32 hs = Hb[(long)s * 64 + lane];
        ax += bf2f_lo(hs) * w;
        ay += bf2f_hi(hs) * w;
    }
    ax += bias[2 * lane];
    ay += bias[2 * lane + 1];
    if (relu) { ax = fmaxf(ax, 0.f); ay = fmaxf(ay, 0.f); }
    OUTb[(long)i * 64 + lane] = f2bf2(ax, ay);
}

// ---------- pooling (batch sorted) ----------
__global__ void k_pool(const uint32* __restrict__ Gb, const int* __restrict__ batch,
                       float* __restrict__ pool, int* __restrict__ cntg, int N) {
    int t = threadIdx.x;                     // 64 threads: feat pair t
    int nb = gridDim.x;
    int chunk = (N + nb - 1) / nb;
    int lo = blockIdx.x * chunk, hi = min(lo + chunk, N);
    if (lo >= hi) return;
    float ax = 0.f, ay = 0.f;
    int cnt = 0;
    int cg = batch[lo];
    for (int i = lo; i < hi; i++) {
        int g = batch[i];
        if (g != cg) {
            atomicAdd(&pool[cg * FEAT + 2 * t], ax);
            atomicAdd(&pool[cg * FEAT + 2 * t + 1], ay);
            if (t == 0) atomicAdd(&cntg[cg], cnt);
            ax = ay = 0.f; cnt = 0; cg = g;
        }
        uint32 v = Gb[(long)i * 64 + t];
        ax += bf2f_lo(v); ay += bf2f_hi(v);
        cnt++;
    }
    atomicAdd(&pool[cg * FEAT + 2 * t], ax);
    atomicAdd(&pool[cg * FEAT + 2 * t + 1], ay);
    if (t == 0) atomicAdd(&cntg[cg], cnt);
}

// ---------- head ----------
__global__ void k_final(const float* __restrict__ pool, const int* __restrict__ cntg,
                        const float* __restrict__ Wlin, const float* __restrict__ blin,
                        float* __restrict__ out) {
    __shared__ float es[FEAT];
    int g = blockIdx.x, t = threadIdx.x;
    float c = (float)max(cntg[g], 1);
    float e = pool[g * FEAT + t] / c;
    es[t] = e;
    out[NGRAPH * 10 + g * FEAT + t] = e;
    __syncthreads();
    if (t < 10) {
        float a = blin[t];
        for (int k = 0; k < FEAT; k++)
            a += es[k] * Wlin[k * 10 + t];
        out[g * 10 + t] = a;
    }
}

// ---------------------------------------------------------------
extern "C" void kernel_launch(void* const* d_in, const int* in_sizes, int n_in,
                              void* d_out, int out_size, void* d_ws, size_t ws_size,
                              hipStream_t stream) {
    const float* x    = (const float*)d_in[0];
    const int*   ei   = (const int*)d_in[1];
    const int*   batch= (const int*)d_in[2];
    const float* W1   = (const float*)d_in[3];
    const float* b1   = (const float*)d_in[4];
    const float* W2   = (const float*)d_in[5];
    const float* b2   = (const float*)d_in[6];
    const float* W3   = (const float*)d_in[7];
    const float* b3   = (const float*)d_in[8];
    const float* Wlin = (const float*)d_in[9];
    const float* blin = (const float*)d_in[10];

    const int N = in_sizes[2];
    const int E = in_sizes[1] / 2;
    const int* src = ei;
    const int* dst = ei + E;

    // ---- workspace carve ----
    char* w = (char*)d_ws;
    auto take = [&](size_t bytes) {
        char* p = w;
        w += (bytes + 255) & ~(size_t)255;
        return p;
    };
    int*    counts = (int*)   take((size_t)N * 4);
    float*  dinv   = (float*) take((size_t)N * 4);
    int*    rowp   = (int*)   take((size_t)(N + 1) * 4);
    int*    cursor = (int*)   take((size_t)N * 4);
    int*    csrc   = (int*)   take((size_t)E * 4);
    float*  cwv    = (float*) take((size_t)E * 4);
    uint32* xb     = (uint32*)take((size_t)N * FEAT * 2);
    uint32* hbuf   = (uint32*)take((size_t)N * FEAT * 2);
    uint32* gbuf   = (uint32*)take((size_t)N * FEAT * 2);
    unsigned short* w1s = (unsigned short*)take(FEAT * FEAT * 2);
    unsigned short* w2s = (unsigned short*)take(FEAT * FEAT * 2);
    unsigned short* w3s = (unsigned short*)take(FEAT * FEAT * 2);
    float*  pool   = (float*) take((size_t)NGRAPH * FEAT * 4);
    int*    cntg   = (int*)   take((size_t)NGRAPH * 4);
    int*    tbase  = (int*)   take((size_t)SBLK * STHR * 4);
    int*    bsum   = (int*)   take((size_t)SBLK * 4);
    int*    bbase  = (int*)   take((size_t)SBLK * 4);
    (void)ws_size; (void)n_in; (void)out_size;

    const int be = (E + 255) / 256;
    const int bn = (N + 255) / 256;

    hipMemsetAsync(counts, 0, (size_t)N * 4, stream);
    hipMemsetAsync(pool,   0, (size_t)NGRAPH * FEAT * 4, stream);
    hipMemsetAsync(cntg,   0, (size_t)NGRAPH * 4, stream);

    // graph preprocessing (CSR by dst); multi-block scan
    k_deg   <<<be, 256, 0, stream>>>(dst, counts, E);
    k_dinv  <<<bn, 256, 0, stream>>>(counts, dinv, N);
    k_scan_a<<<SBLK, STHR, 0, stream>>>(counts, tbase, bsum, N);
    k_scan_b<<<1, SBLK, 0, stream>>>(bsum, bbase, rowp, N);
    k_scan_c<<<SBLK, STHR, 0, stream>>>(counts, tbase, bbase, rowp, cursor, N);
    k_fill  <<<be, 256, 0, stream>>>(src, dst, dinv, cursor, csrc, cwv, E);

    // casts / weight swizzles
    k_cast<<<2048, 256, 0, stream>>>(x, xb, (long)N * FEAT / 2);
    k_wswz<<<8, 256, 0, stream>>>(W1, w1s);
    k_wswz<<<8, 256, 0, stream>>>(W2, w2s);
    k_wswz<<<8, 256, 0, stream>>>(W3, w3s);

    const int gemm_blocks = (N + 63) / 64;
    const int agg_blocks  = (N + 3) / 4;

    // layer 1
    k_gemm<<<gemm_blocks, 256, 0, stream>>>(xb, w1s, (unsigned short*)hbuf, N);
    k_agg <<<agg_blocks, 256, 0, stream>>>(hbuf, rowp, csrc, cwv, dinv, b1, gbuf, N, 1);
    // layer 2
    k_gemm<<<gemm_blocks, 256, 0, stream>>>(gbuf, w2s, (unsigned short*)hbuf, N);
    k_agg <<<agg_blocks, 256, 0, stream>>>(hbuf, rowp, csrc, cwv, dinv, b2, gbuf, N, 1);
    // layer 3
    k_gemm<<<gemm_blocks, 256, 0, stream>>>(gbuf, w3s, (unsigned short*)hbuf, N);
    k_agg <<<agg_blocks, 256, 0, stream>>>(hbuf, rowp, csrc, cwv, dinv, b3, gbuf, N, 0);

    // pooling + head
    k_pool <<<1024, 64, 0, stream>>>(gbuf, batch, pool, cntg, N);
    k_final<<<NGRAPH, 128, 0, stream>>>(pool, cntg, Wlin, blin, (float*)d_out);
}

// Round 6
// 565.781 us; speedup vs baseline: 3.7668x; 1.4807x over previous
//
#include <hip/hip_runtime.h>
#include <hip/hip_bf16.h>
#include <stdint.h>

typedef unsigned int uint32;
typedef __attribute__((ext_vector_type(8))) short short8;   // 8 bf16 = 4 VGPRs
typedef __attribute__((ext_vector_type(4))) float float4v;  // MFMA C/D

#define FEAT 128
#define NGRAPH 64
#define SBLK 256     // scan blocks
#define STHR 256     // scan threads/block
#define SSEG 2       // elements per thread (256*256*2 = 131072 >= N)

// ---------- bf16 helpers ----------
__device__ __forceinline__ float bf2f_lo(uint32 v) {
    union { uint32 i; float f; } u; u.i = v << 16; return u.f;
}
__device__ __forceinline__ float bf2f_hi(uint32 v) {
    union { uint32 i; float f; } u; u.i = v & 0xffff0000u; return u.f;
}
__device__ __forceinline__ unsigned short f2bf(float f) {
    uint32 u = __builtin_bit_cast(uint32, f);
    uint32 r = (u + 0x7fffu + ((u >> 16) & 1u)) >> 16;      // RNE
    return (unsigned short)r;
}
__device__ __forceinline__ uint32 f2bf2(float lo, float hi) {
    return (uint32)f2bf(lo) | ((uint32)f2bf(hi) << 16);
}

// ---------- graph preprocessing ----------
__global__ void k_deg(const int* __restrict__ dst, int* __restrict__ counts, int E) {
    int e = blockIdx.x * blockDim.x + threadIdx.x;
    if (e < E) atomicAdd(&counts[dst[e]], 1);
}

__global__ void k_dinv(const int* __restrict__ counts, float* __restrict__ dinv, int N) {
    int i = blockIdx.x * blockDim.x + threadIdx.x;
    if (i < N) dinv[i] = rsqrtf((float)counts[i] + 1.0f);   // deg = in-deg + self loop
}

// ---- multi-block exclusive scan ----
__global__ void k_scan_a(const int* __restrict__ counts, int* __restrict__ tbase,
                         int* __restrict__ bsum, int N) {
    __shared__ int sc[STHR];
    int t = threadIdx.x, b = blockIdx.x;
    int g = b * STHR + t;
    int lo = g * SSEG;
    int s = 0;
#pragma unroll
    for (int j = 0; j < SSEG; j++) {
        int i = lo + j;
        if (i < N) s += counts[i];
    }
    sc[t] = s;
    __syncthreads();
    for (int off = 1; off < STHR; off <<= 1) {
        int v = (t >= off) ? sc[t - off] : 0;
        __syncthreads();
        sc[t] += v;
        __syncthreads();
    }
    tbase[g] = sc[t] - s;
    if (t == STHR - 1) bsum[b] = sc[t];
}

__global__ void k_scan_b(const int* __restrict__ bsum, int* __restrict__ bbase,
                         int* __restrict__ rowp, int N) {
    __shared__ int sc[SBLK];
    int t = threadIdx.x;
    int s = bsum[t];
    sc[t] = s;
    __syncthreads();
    for (int off = 1; off < SBLK; off <<= 1) {
        int v = (t >= off) ? sc[t - off] : 0;
        __syncthreads();
        sc[t] += v;
        __syncthreads();
    }
    bbase[t] = sc[t] - s;
    if (t == SBLK - 1) rowp[N] = sc[t];
}

__global__ void k_scan_c(const int* __restrict__ counts, const int* __restrict__ tbase,
                         const int* __restrict__ bbase, int* __restrict__ rowp,
                         int* __restrict__ cursor, int N) {
    int t = threadIdx.x, b = blockIdx.x;
    int g = b * STHR + t;
    int base = bbase[b] + tbase[g];
    int lo = g * SSEG;
#pragma unroll
    for (int j = 0; j < SSEG; j++) {
        int i = lo + j;
        if (i < N) { rowp[i] = base; cursor[i] = base; base += counts[i]; }
    }
}

__global__ void k_fill(const int* __restrict__ src, const int* __restrict__ dst,
                       const float* __restrict__ dinv, int* __restrict__ cursor,
                       int* __restrict__ csrc, float* __restrict__ cw, int E) {
    int e = blockIdx.x * blockDim.x + threadIdx.x;
    if (e >= E) return;
    int s = src[e], d = dst[e];
    int pos = atomicAdd(&cursor[d], 1);
    csrc[pos] = s;
    cw[pos] = dinv[s] * dinv[d];
}

// ---------- cast x f32 -> bf16 (packed) ----------
__global__ void k_cast(const float* __restrict__ X, uint32* __restrict__ Xb, long n2) {
    long i = (long)blockIdx.x * blockDim.x + threadIdx.x;
    long stride = (long)gridDim.x * blockDim.x;
    for (; i < n2; i += stride) {
        float2 v = *(const float2*)(X + 2 * i);
        Xb[i] = f2bf2(v.x, v.y);
    }
}

// ---------- pre-swizzle W into MFMA B-fragment order, bf16 ----
__global__ void k_wswz(const float* __restrict__ W, unsigned short* __restrict__ out) {
    int e = blockIdx.x * blockDim.x + threadIdx.x;          // 2048 entries
    if (e >= 2048) return;
    int kt = e >> 9, ct = (e >> 6) & 7, lane = e & 63;
    int krow = kt * 32 + (lane >> 4) * 8;
    int col = ct * 16 + (lane & 15);
#pragma unroll
    for (int j = 0; j < 8; j++)
        out[e * 8 + j] = f2bf(W[(krow + j) * FEAT + col]);
}

// ---------- MFMA GEMM ----------
__global__ void k_gemm(const uint32* __restrict__ Xb,
                       const unsigned short* __restrict__ Wswz,
                       unsigned short* __restrict__ Hb, int N) {
    __shared__ unsigned short Wl[FEAT * FEAT];              // 32 KB
    {
        const uint4* Wg = (const uint4*)Wswz;
        uint4* Ws = (uint4*)Wl;
        for (int i = threadIdx.x; i < 2048; i += 256) Ws[i] = Wg[i];
    }
    __syncthreads();

    int wave = threadIdx.x >> 6, lane = threadIdx.x & 63;
    int r0 = (blockIdx.x * 4 + wave) * 16;
    if (r0 >= N) return;
    int m = lane & 15, q = lane >> 4;

    int arow = r0 + m; if (arow >= N) arow = N - 1;
    const short8* Arow = (const short8*)((const unsigned short*)Xb + (long)arow * FEAT);
    short8 a0 = Arow[q + 0];
    short8 a1 = Arow[4 + q];
    short8 a2 = Arow[8 + q];
    short8 a3 = Arow[12 + q];

    const short8* Bl = (const short8*)Wl;
    float4v acc[8];
#pragma unroll
    for (int ct = 0; ct < 8; ct++) acc[ct] = (float4v){0.f, 0.f, 0.f, 0.f};

#pragma unroll
    for (int ct = 0; ct < 8; ct++) {
        acc[ct] = __builtin_amdgcn_mfma_f32_16x16x32_bf16(a0, Bl[(0 * 8 + ct) * 64 + lane], acc[ct], 0, 0, 0);
        acc[ct] = __builtin_amdgcn_mfma_f32_16x16x32_bf16(a1, Bl[(1 * 8 + ct) * 64 + lane], acc[ct], 0, 0, 0);
        acc[ct] = __builtin_amdgcn_mfma_f32_16x16x32_bf16(a2, Bl[(2 * 8 + ct) * 64 + lane], acc[ct], 0, 0, 0);
        acc[ct] = __builtin_amdgcn_mfma_f32_16x16x32_bf16(a3, Bl[(3 * 8 + ct) * 64 + lane], acc[ct], 0, 0, 0);
    }

    // C/D layout: col = lane&15, row = q*4 + reg
#pragma unroll
    for (int ct = 0; ct < 8; ct++) {
#pragma unroll
        for (int reg = 0; reg < 4; reg++) {
            int row = r0 + q * 4 + reg;
            if (row < N) Hb[(long)row * FEAT + ct * 16 + m] = f2bf(acc[ct][reg]);
        }
    }
}

// ---------- aggregation: unroll-by-8 edge loop for memory-level parallelism ----------
// R5 was latency-bound: dependent csrc->gather chain, ~1 outstanding gather/wave.
// Batch 8 indices (contiguous), then 8 independent 256B row gathers in flight.
__global__ void k_agg(const uint32* __restrict__ Hb,
                      const int* __restrict__ rowp,
                      const int* __restrict__ csrc, const float* __restrict__ cw,
                      const float* __restrict__ dinv, const float* __restrict__ bias,
                      uint32* __restrict__ OUTb, int N, int relu) {
    int wave = threadIdx.x >> 6, lane = threadIdx.x & 63;
    int i = blockIdx.x * 4 + wave;
    if (i >= N) return;
    float di = dinv[i];
    uint32 hv = Hb[(long)i * 64 + lane];
    float sw = di * di;
    float ax = bf2f_lo(hv) * sw, ay = bf2f_hi(hv) * sw;
    int e0 = rowp[i], e1 = rowp[i + 1];
    int e = e0;
    for (; e + 8 <= e1; e += 8) {
        int   s[8];
        float w[8];
        uint32 h[8];
#pragma unroll
        for (int j = 0; j < 8; j++) { s[j] = csrc[e + j]; w[j] = cw[e + j]; }
#pragma unroll
        for (int j = 0; j < 8; j++) h[j] = Hb[(long)s[j] * 64 + lane];
#pragma unroll
        for (int j = 0; j < 8; j++) {
            ax += bf2f_lo(h[j]) * w[j];
            ay += bf2f_hi(h[j]) * w[j];
        }
    }
    {   // remainder (<8 edges), still index-batched
        int   s[8];
        float w[8];
        uint32 h[8];
        int r = e1 - e;
#pragma unroll
        for (int j = 0; j < 8; j++)
            if (j < r) { s[j] = csrc[e + j]; w[j] = cw[e + j]; }
#pragma unroll
        for (int j = 0; j < 8; j++)
            if (j < r) h[j] = Hb[(long)s[j] * 64 + lane];
#pragma unroll
        for (int j = 0; j < 8; j++)
            if (j < r) {
                ax += bf2f_lo(h[j]) * w[j];
                ay += bf2f_hi(h[j]) * w[j];
            }
    }
    ax += bias[2 * lane];
    ay += bias[2 * lane + 1];
    if (relu) { ax = fmaxf(ax, 0.f); ay = fmaxf(ay, 0.f); }
    OUTb[(long)i * 64 + lane] = f2bf2(ax, ay);
}

// ---------- pooling (batch sorted) ----------
__global__ void k_pool(const uint32* __restrict__ Gb, const int* __restrict__ batch,
                       float* __restrict__ pool, int* __restrict__ cntg, int N) {
    int t = threadIdx.x;                     // 64 threads: feat pair t
    int nb = gridDim.x;
    int chunk = (N + nb - 1) / nb;
    int lo = blockIdx.x * chunk, hi = min(lo + chunk, N);
    if (lo >= hi) return;
    float ax = 0.f, ay = 0.f;
    int cnt = 0;
    int cg = batch[lo];
    for (int i = lo; i < hi; i++) {
        int g = batch[i];
        if (g != cg) {
            atomicAdd(&pool[cg * FEAT + 2 * t], ax);
            atomicAdd(&pool[cg * FEAT + 2 * t + 1], ay);
            if (t == 0) atomicAdd(&cntg[cg], cnt);
            ax = ay = 0.f; cnt = 0; cg = g;
        }
        uint32 v = Gb[(long)i * 64 + t];
        ax += bf2f_lo(v); ay += bf2f_hi(v);
        cnt++;
    }
    atomicAdd(&pool[cg * FEAT + 2 * t], ax);
    atomicAdd(&pool[cg * FEAT + 2 * t + 1], ay);
    if (t == 0) atomicAdd(&cntg[cg], cnt);
}

// ---------- head ----------
__global__ void k_final(const float* __restrict__ pool, const int* __restrict__ cntg,
                        const float* __restrict__ Wlin, const float* __restrict__ blin,
                        float* __restrict__ out) {
    __shared__ float es[FEAT];
    int g = blockIdx.x, t = threadIdx.x;
    float c = (float)max(cntg[g], 1);
    float e = pool[g * FEAT + t] / c;
    es[t] = e;
    out[NGRAPH * 10 + g * FEAT + t] = e;
    __syncthreads();
    if (t < 10) {
        float a = blin[t];
        for (int k = 0; k < FEAT; k++)
            a += es[k] * Wlin[k * 10 + t];
        out[g * 10 + t] = a;
    }
}

// ---------------------------------------------------------------
extern "C" void kernel_launch(void* const* d_in, const int* in_sizes, int n_in,
                              void* d_out, int out_size, void* d_ws, size_t ws_size,
                              hipStream_t stream) {
    const float* x    = (const float*)d_in[0];
    const int*   ei   = (const int*)d_in[1];
    const int*   batch= (const int*)d_in[2];
    const float* W1   = (const float*)d_in[3];
    const float* b1   = (const float*)d_in[4];
    const float* W2   = (const float*)d_in[5];
    const float* b2   = (const float*)d_in[6];
    const float* W3   = (const float*)d_in[7];
    const float* b3   = (const float*)d_in[8];
    const float* Wlin = (const float*)d_in[9];
    const float* blin = (const float*)d_in[10];

    const int N = in_sizes[2];
    const int E = in_sizes[1] / 2;
    const int* src = ei;
    const int* dst = ei + E;

    // ---- workspace carve ----
    char* w = (char*)d_ws;
    auto take = [&](size_t bytes) {
        char* p = w;
        w += (bytes + 255) & ~(size_t)255;
        return p;
    };
    int*    counts = (int*)   take((size_t)N * 4);
    float*  dinv   = (float*) take((size_t)N * 4);
    int*    rowp   = (int*)   take((size_t)(N + 1) * 4);
    int*    cursor = (int*)   take((size_t)N * 4);
    int*    csrc   = (int*)   take((size_t)E * 4);
    float*  cwv    = (float*) take((size_t)E * 4);
    uint32* xb     = (uint32*)take((size_t)N * FEAT * 2);
    uint32* hbuf   = (uint32*)take((size_t)N * FEAT * 2);
    uint32* gbuf   = (uint32*)take((size_t)N * FEAT * 2);
    unsigned short* w1s = (unsigned short*)take(FEAT * FEAT * 2);
    unsigned short* w2s = (unsigned short*)take(FEAT * FEAT * 2);
    unsigned short* w3s = (unsigned short*)take(FEAT * FEAT * 2);
    float*  pool   = (float*) take((size_t)NGRAPH * FEAT * 4);
    int*    cntg   = (int*)   take((size_t)NGRAPH * 4);
    int*    tbase  = (int*)   take((size_t)SBLK * STHR * 4);
    int*    bsum   = (int*)   take((size_t)SBLK * 4);
    int*    bbase  = (int*)   take((size_t)SBLK * 4);
    (void)ws_size; (void)n_in; (void)out_size;

    const int be = (E + 255) / 256;
    const int bn = (N + 255) / 256;

    hipMemsetAsync(counts, 0, (size_t)N * 4, stream);
    hipMemsetAsync(pool,   0, (size_t)NGRAPH * FEAT * 4, stream);
    hipMemsetAsync(cntg,   0, (size_t)NGRAPH * 4, stream);

    // graph preprocessing (CSR by dst); multi-block scan
    k_deg   <<<be, 256, 0, stream>>>(dst, counts, E);
    k_dinv  <<<bn, 256, 0, stream>>>(counts, dinv, N);
    k_scan_a<<<SBLK, STHR, 0, stream>>>(counts, tbase, bsum, N);
    k_scan_b<<<1, SBLK, 0, stream>>>(bsum, bbase, rowp, N);
    k_scan_c<<<SBLK, STHR, 0, stream>>>(counts, tbase, bbase, rowp, cursor, N);
    k_fill  <<<be, 256, 0, stream>>>(src, dst, dinv, cursor, csrc, cwv, E);

    // casts / weight swizzles
    k_cast<<<2048, 256, 0, stream>>>(x, xb, (long)N * FEAT / 2);
    k_wswz<<<8, 256, 0, stream>>>(W1, w1s);
    k_wswz<<<8, 256, 0, stream>>>(W2, w2s);
    k_wswz<<<8, 256, 0, stream>>>(W3, w3s);

    const int gemm_blocks = (N + 63) / 64;
    const int agg_blocks  = (N + 3) / 4;

    // layer 1
    k_gemm<<<gemm_blocks, 256, 0, stream>>>(xb, w1s, (unsigned short*)hbuf, N);
    k_agg <<<agg_blocks, 256, 0, stream>>>(hbuf, rowp, csrc, cwv, dinv, b1, gbuf, N, 1);
    // layer 2
    k_gemm<<<gemm_blocks, 256, 0, stream>>>(gbuf, w2s, (unsigned short*)hbuf, N);
    k_agg <<<agg_blocks, 256, 0, stream>>>(hbuf, rowp, csrc, cwv, dinv, b2, gbuf, N, 1);
    // layer 3
    k_gemm<<<gemm_blocks, 256, 0, stream>>>(gbuf, w3s, (unsigned short*)hbuf, N);
    k_agg <<<agg_blocks, 256, 0, stream>>>(hbuf, rowp, csrc, cwv, dinv, b3, gbuf, N, 0);

    // pooling + head
    k_pool <<<1024, 64, 0, stream>>>(gbuf, batch, pool, cntg, N);
    k_final<<<NGRAPH, 128, 0, stream>>>(pool, cntg, Wlin, blin, (float*)d_out);
}